// Round 9
// baseline (383.533 us; speedup 1.0000x reference)
//
#include <hip/hip_runtime.h>

// Problem constants
#define CI    16
#define CO    16
#define HID   256
#define IMGH  128
#define IMGW  128
#define RSTR  136            // shPatch row stride in shorts (272 B, 16B-aligned)
#define RLEN  130            // 128 + 2 halo
#define W2PROW 2560          // shorts per k-row of W2p: 256 threads * 10 (9 cols + pad)
#define MAXEVT 512

typedef float f32x2 __attribute__((ext_vector_type(2)));

__device__ __host__ __forceinline__ short f2bf(float f) {
  union { float f; unsigned u; } c; c.f = f;
  unsigned b = c.u + 0x7FFFu + ((c.u >> 16) & 1u);   // RNE
  return (short)(b >> 16);
}
__device__ __forceinline__ float blo(unsigned u){ return __uint_as_float(u << 16); }
__device__ __forceinline__ float bhi(unsigned u){ return __uint_as_float(u & 0xFFFF0000u); }

// ---------------------------------------------------------------------------
// Prep: W2 [256][2304] fp32 -> W2p [k][t:256][10] bf16; thread t's 9 cols are
// 9t..9t+8 (col = o*144 + ci*9 + q), padded to 10 shorts = 5 dwords.
// ---------------------------------------------------------------------------
__global__ void prep_w2p(const float* __restrict__ W2, short* __restrict__ W2p) {
  const int k = blockIdx.x;          // 0..255
  const int t = threadIdx.x;         // 0..255
  const float* src = W2 + k * (CO * 144) + t * 9;
  short* dst = W2p + k * W2PROW + t * 10;
  #pragma unroll
  for (int q = 0; q < 9; ++q) dst[q] = f2bf(src[q]);
  dst[9] = 0;
}

// ---------------------------------------------------------------------------
// v20 = v19 breakpoint-sweep with the latency chains removed.
// Post-mortem v19 (160 us, VALUBusy 31%, occ 18%): latency-bound, not
// throughput-bound. Chains: (1) per-pixel 4-level shfl reduce (~50cyc DS
// latency/level x 128 px ~ 25k cyc/wave); (2) bucket-0's ~128 back-to-back
// events with only ~60cyc cover vs ~200cyc L2; (3) 48 ds_read_u16/row.
// v20: (1) batch 16 px -> ONE reduce-scatter butterfly (15 shfl per 16 px,
//        dx folded in BEFORE the tree since dx is lane-uniform per px;
//        final P[0] at lane c15 = sum for x = xb + c15);
//      (2) bucket-0 events processed in PAIRS with 1-pair row lookahead
//        (events commute: S += contributions; odd leftover applied first);
//      (3) per-batch vector patch loads (b128+b128+b32 per row, RSTR 136
//        for 16B alignment), taps unpacked from regs (CSE across the 16 px).
// Thread t = (o=t>>4, ci=t&15) owns cols 9t..9t+8; S (S0,S1) as f32x2 S[9].
// grid = 4 batches * 128 rows = 512 blocks x 256 threads; no MFMA.
// ---------------------------------------------------------------------------
__global__ __launch_bounds__(256, 2)
void ngconv_sweep(const float* __restrict__ in, const float* __restrict__ foa,
                  const float* __restrict__ W1, const float* __restrict__ b1,
                  const short* __restrict__ W2p, const float* __restrict__ b2,
                  float* __restrict__ out) {
  __shared__ short shPatch[48 * RSTR];     // reflect-extended rows, 13.1 KB
  __shared__ float shO[CO * 129];          // output staging, 8.3 KB
  __shared__ unsigned evOff[MAXEVT];       // W2p byte offset per event
  __shared__ float evC[MAXEVT];            // signed c coef
  __shared__ float evA[MAXEVT];            // signed a coef
  __shared__ int bstart[IMGW + 1];         // bucket prefix
  __shared__ int cnt[IMGW];                // histogram / cursors
  __shared__ int nentSh;

  const int tid  = threadIdx.x;
  const int o    = tid >> 4;        // output channel
  const int ic   = tid & 15;        // input channel
  const int c15  = tid & 15;        // reduce-group lane (== ic)

  const int blk = blockIdx.x;
  const int b = blk >> 7;
  const int y = blk & 127;

  const float fx = foa[b * 2 + 0];
  const float fy = foa[b * 2 + 1];
  const float dyv = (float)y - fy;
  const int ry0 = (y == 0) ? 1 : (y - 1);
  const int ry2 = (y == IMGH - 1) ? (IMGH - 2) : (y + 1);

  // ---- patch rows (v14's verified setup, RSTR=136)
  for (int e = tid; e < 48 * RLEN; e += 256) {
    int r = e / RLEN, xx = e - r * RLEN;
    int i2 = r / 3, dyr = r - i2 * 3;
    int ryr = (dyr == 0) ? ry0 : ((dyr == 1) ? y : ry2);
    int x = xx - 1;
    x = (x < 0) ? 1 : ((x > IMGW - 1) ? (IMGW - 2) : x);   // reflect
    shPatch[r * RSTR + xx] = f2bf(in[((b * CI + i2) * IMGH + ryr) * IMGW + x]);
  }

  for (int e = tid; e < IMGW; e += 256) cnt[e] = 0;
  __syncthreads();

  // ---- bucketing: thread tid handles k = tid (identical to v19, verified)
  float ka = W1[tid];                         // W1[0][k]
  float kc = fmaf(dyv, W1[HID + tid], b1[tid]);
  bool act0 = false;
  int xe = -1;
  if (ka != 0.f) {
    float th = fx - kc / ka;                  // breakpoint in x
    if (ka > 0.f) {
      act0 = (th < 0.f);
      if (th >= 0.f && th < 127.f) xe = (int)floorf(th) + 1;
    } else {
      act0 = (th > 0.f);
      if (th > 0.f && th < 127.f) xe = (int)floorf(th) + 1;
    }
  } else {
    act0 = (kc > 0.f);
  }
  if (act0)   atomicAdd(&cnt[0], 1);
  if (xe > 0) atomicAdd(&cnt[xe], 1);
  __syncthreads();
  if (tid == 0) {
    int s = 0;
    for (int x = 0; x < IMGW; ++x) { bstart[x] = s; s += cnt[x]; }
    bstart[IMGW] = s; nentSh = s;
  }
  __syncthreads();
  for (int e = tid; e < IMGW; e += 256) cnt[e] = bstart[e];   // cursors
  __syncthreads();
  if (act0) {
    int p = atomicAdd(&cnt[0], 1);
    evOff[p] = (unsigned)tid * (W2PROW * 2);
    evC[p] = kc; evA[p] = ka;
  }
  if (xe > 0) {
    int p = atomicAdd(&cnt[xe], 1);
    float sg = (ka > 0.f) ? 1.f : -1.f;
    evOff[p] = (unsigned)tid * (W2PROW * 2);
    evC[p] = sg * kc; evA[p] = sg * ka;
  }

  // ---- S init: S0 = b2, S1 = 0
  f32x2 S[9];
  {
    const float* bp = b2 + tid * 9;
    #pragma unroll
    for (int q = 0; q < 9; ++q) S[q] = (f32x2){bp[q], 0.f};
  }
  __syncthreads();
  const int nent  = nentSh;
  const int nent0 = bstart[1];               // bucket-0 (active at x=0) count
  const char* W2pc = (const char*)W2p;

  // ================= bucket-0: paired events, 1-pair lookahead =============
  {
    const int od = nent0 & 1;
    if (od) {                                // odd leftover first (commutes)
      unsigned off = evOff[nent0 - 1];
      f32x2 ca = (f32x2){evC[nent0 - 1], evA[nent0 - 1]};
      const unsigned* gp = (const unsigned*)(W2pc + off) + tid * 5;
      unsigned q0 = gp[0], q1 = gp[1], q2 = gp[2], q3 = gp[3], q4 = gp[4];
      S[0] += (f32x2){blo(q0), blo(q0)} * ca;
      S[1] += (f32x2){bhi(q0), bhi(q0)} * ca;
      S[2] += (f32x2){blo(q1), blo(q1)} * ca;
      S[3] += (f32x2){bhi(q1), bhi(q1)} * ca;
      S[4] += (f32x2){blo(q2), blo(q2)} * ca;
      S[5] += (f32x2){bhi(q2), bhi(q2)} * ca;
      S[6] += (f32x2){blo(q3), blo(q3)} * ca;
      S[7] += (f32x2){bhi(q3), bhi(q3)} * ca;
      S[8] += (f32x2){blo(q4), blo(q4)} * ca;
    }
    const int npair = (nent0 - od) >> 1;
    unsigned A0=0,A1=0,A2=0,A3=0,A4=0,A5=0,A6=0,A7=0,A8=0,A9=0;
    float Ca=0.f, Aa=0.f, Cb=0.f, Ab=0.f;
    unsigned NO0=0, NO1=0; float NCa=0.f, NAa=0.f, NCb=0.f, NAb=0.f;
    if (npair > 0) {
      unsigned o0 = evOff[0], o1 = evOff[1];
      Ca = evC[0]; Aa = evA[0]; Cb = evC[1]; Ab = evA[1];
      const unsigned* g0 = (const unsigned*)(W2pc + o0) + tid * 5;
      const unsigned* g1 = (const unsigned*)(W2pc + o1) + tid * 5;
      A0=g0[0]; A1=g0[1]; A2=g0[2]; A3=g0[3]; A4=g0[4];
      A5=g1[0]; A6=g1[1]; A7=g1[2]; A8=g1[3]; A9=g1[4];
    }
    if (npair > 1) {
      NO0 = evOff[2]; NO1 = evOff[3];
      NCa = evC[2]; NAa = evA[2]; NCb = evC[3]; NAb = evA[3];
    }
    #pragma unroll 1
    for (int i = 0; i < npair; ++i) {
      unsigned M0=0,M1=0,M2=0,M3=0,M4=0,M5=0,M6=0,M7=0,M8=0,M9=0;
      if (i + 1 < npair) {                   // prefetch rows for pair i+1
        const unsigned* g0 = (const unsigned*)(W2pc + NO0) + tid * 5;
        const unsigned* g1 = (const unsigned*)(W2pc + NO1) + tid * 5;
        M0=g0[0]; M1=g0[1]; M2=g0[2]; M3=g0[3]; M4=g0[4];
        M5=g1[0]; M6=g1[1]; M7=g1[2]; M8=g1[3]; M9=g1[4];
      }
      unsigned TO0=0, TO1=0; float TCa=0.f, TAa=0.f, TCb=0.f, TAb=0.f;
      if (i + 2 < npair) {                   // prefetch meta for pair i+2
        TO0 = evOff[2*i+4]; TO1 = evOff[2*i+5];
        TCa = evC[2*i+4]; TAa = evA[2*i+4]; TCb = evC[2*i+5]; TAb = evA[2*i+5];
      }
      f32x2 ca = (f32x2){Ca, Aa}, cb = (f32x2){Cb, Ab};
      S[0] += (f32x2){blo(A0), blo(A0)} * ca + (f32x2){blo(A5), blo(A5)} * cb;
      S[1] += (f32x2){bhi(A0), bhi(A0)} * ca + (f32x2){bhi(A5), bhi(A5)} * cb;
      S[2] += (f32x2){blo(A1), blo(A1)} * ca + (f32x2){blo(A6), blo(A6)} * cb;
      S[3] += (f32x2){bhi(A1), bhi(A1)} * ca + (f32x2){bhi(A6), bhi(A6)} * cb;
      S[4] += (f32x2){blo(A2), blo(A2)} * ca + (f32x2){blo(A7), blo(A7)} * cb;
      S[5] += (f32x2){bhi(A2), bhi(A2)} * ca + (f32x2){bhi(A7), bhi(A7)} * cb;
      S[6] += (f32x2){blo(A3), blo(A3)} * ca + (f32x2){blo(A8), blo(A8)} * cb;
      S[7] += (f32x2){bhi(A3), bhi(A3)} * ca + (f32x2){bhi(A8), bhi(A8)} * cb;
      S[8] += (f32x2){blo(A4), blo(A4)} * ca + (f32x2){blo(A9), blo(A9)} * cb;
      A0=M0; A1=M1; A2=M2; A3=M3; A4=M4; A5=M5; A6=M6; A7=M7; A8=M8; A9=M9;
      Ca=NCa; Aa=NAa; Cb=NCb; Ab=NAb;
      NO0=TO0; NO1=TO1; NCa=TCa; NAa=TAa; NCb=TCb; NAb=TAb;
    }
  }

  // ================= sweep: 8 batches of 16 px ============================
  // event pipeline prime (2-deep, crossings only: events nent0..nent)
  unsigned r0=0, r1=0, r2=0, r3=0, r4=0;
  float cC=0.f, cA=0.f;
  unsigned nOff=0; float nC=0.f, nA=0.f;
  if (nent > nent0) {
    unsigned offs0 = evOff[nent0]; cC = evC[nent0]; cA = evA[nent0];
    const unsigned* gp = (const unsigned*)(W2pc + offs0) + tid * 5;
    r0 = gp[0]; r1 = gp[1]; r2 = gp[2]; r3 = gp[3]; r4 = gp[4];
  }
  if (nent > nent0 + 1) { nOff = evOff[nent0+1]; nC = evC[nent0+1]; nA = evA[nent0+1]; }

  const short* pr0 = &shPatch[(ic * 3 + 0) * RSTR];
  const short* pr1 = &shPatch[(ic * 3 + 1) * RSTR];
  const short* pr2 = &shPatch[(ic * 3 + 2) * RSTR];

  int aptr = nent0;

  #pragma unroll 1
  for (int xb = 0; xb < IMGW; xb += 16) {
    // batch patch segments: 18 shorts per row -> 9 dwords (16B-aligned)
    unsigned sg[3][9];
    {
      const uint4* s0 = (const uint4*)(pr0 + xb);
      const uint4* s1 = (const uint4*)(pr1 + xb);
      const uint4* s2 = (const uint4*)(pr2 + xb);
      uint4 a = s0[0], b4 = s0[1]; unsigned c0 = ((const unsigned*)(pr0 + xb))[8];
      sg[0][0]=a.x; sg[0][1]=a.y; sg[0][2]=a.z; sg[0][3]=a.w;
      sg[0][4]=b4.x; sg[0][5]=b4.y; sg[0][6]=b4.z; sg[0][7]=b4.w; sg[0][8]=c0;
      a = s1[0]; b4 = s1[1]; c0 = ((const unsigned*)(pr1 + xb))[8];
      sg[1][0]=a.x; sg[1][1]=a.y; sg[1][2]=a.z; sg[1][3]=a.w;
      sg[1][4]=b4.x; sg[1][5]=b4.y; sg[1][6]=b4.z; sg[1][7]=b4.w; sg[1][8]=c0;
      a = s2[0]; b4 = s2[1]; c0 = ((const unsigned*)(pr2 + xb))[8];
      sg[2][0]=a.x; sg[2][1]=a.y; sg[2][2]=a.z; sg[2][3]=a.w;
      sg[2][4]=b4.x; sg[2][5]=b4.y; sg[2][6]=b4.z; sg[2][7]=b4.w; sg[2][8]=c0;
    }
    int ends[16];
    #pragma unroll
    for (int j = 0; j < 16; ++j) ends[j] = bstart[xb + j + 1];

    float pv[16];
    #pragma unroll
    for (int j = 0; j < 16; ++j) {
      // apply this pixel's crossing events (block-uniform control flow)
      while (aptr < ends[j]) {
        unsigned tOff = 0; float tC = 0.f, tA = 0.f;
        if (aptr + 2 < nent) { tOff = evOff[aptr+2]; tC = evC[aptr+2]; tA = evA[aptr+2]; }
        unsigned m0=0, m1=0, m2=0, m3=0, m4=0;
        if (aptr + 1 < nent) {
          const unsigned* gp = (const unsigned*)(W2pc + nOff) + tid * 5;
          m0 = gp[0]; m1 = gp[1]; m2 = gp[2]; m3 = gp[3]; m4 = gp[4];
        }
        f32x2 ca2 = (f32x2){cC, cA};
        S[0] += (f32x2){blo(r0), blo(r0)} * ca2;
        S[1] += (f32x2){bhi(r0), bhi(r0)} * ca2;
        S[2] += (f32x2){blo(r1), blo(r1)} * ca2;
        S[3] += (f32x2){bhi(r1), bhi(r1)} * ca2;
        S[4] += (f32x2){blo(r2), blo(r2)} * ca2;
        S[5] += (f32x2){bhi(r2), bhi(r2)} * ca2;
        S[6] += (f32x2){blo(r3), blo(r3)} * ca2;
        S[7] += (f32x2){bhi(r3), bhi(r3)} * ca2;
        S[8] += (f32x2){blo(r4), blo(r4)} * ca2;
        r0 = m0; r1 = m1; r2 = m2; r3 = m3; r4 = m4; cC = nC; cA = nA;
        nOff = tOff; nC = tC; nA = tA;
        ++aptr;
      }
      // contraction: taps j,j+1,j+2 of each row (static idx -> 1-op unpacks,
      // CSE'd across the 16 unrolled pixels)
      f32x2 p = (f32x2){0.f, 0.f};
      #pragma unroll
      for (int r = 0; r < 3; ++r) {
        #pragma unroll
        for (int t = 0; t < 3; ++t) {
          int idx = j + t;
          unsigned dw = sg[r][idx >> 1];
          float v = (idx & 1) ? bhi(dw) : blo(dw);
          p += (f32x2){v, v} * S[r * 3 + t];
        }
      }
      pv[j] = fmaf((float)(xb + j) - fx, p[1], p[0]);   // dx uniform per px
    }

    // ---- ONE reduce-scatter butterfly for all 16 px (v14's tree):
    // final P[0] at lane c15 = sum over 16 lanes of pv[c15]
    float P[16];
    #pragma unroll
    for (int t = 0; t < 16; ++t) P[t] = pv[t];
    #pragma unroll
    for (int m = 8; m >= 1; m >>= 1) {
      const bool hi = (c15 & m) != 0;
      #pragma unroll
      for (int j = 0; j < m; ++j) {
        float keep = hi ? P[j + m] : P[j];
        float send = hi ? P[j] : P[j + m];
        float recv = __shfl_xor(send, m, 64);
        P[j] = keep + recv;
      }
    }
    shO[o * 129 + xb + c15] = P[0];
  }

  // ---- coalesced flush (full 512 B rows)
  __syncthreads();
  #pragma unroll
  for (int u = 0; u < 2; ++u) {
    int f = u * 256 + tid;
    int row = f >> 5, c4 = f & 31;
    float4 v;
    v.x = shO[row * 129 + c4 * 4 + 0];
    v.y = shO[row * 129 + c4 * 4 + 1];
    v.z = shO[row * 129 + c4 * 4 + 2];
    v.w = shO[row * 129 + c4 * 4 + 3];
    *(float4*)&out[((b * CO + row) * IMGH + y) * IMGW + c4 * 4] = v;
  }
}

// ---------------------------------------------------------------------------
extern "C" void kernel_launch(void* const* d_in, const int* in_sizes, int n_in,
                              void* d_out, int out_size, void* d_ws, size_t ws_size,
                              hipStream_t stream) {
  const float* in  = (const float*)d_in[0];   // [4,16,128,128]
  const float* foa = (const float*)d_in[1];   // [4,2]
  const float* W1  = (const float*)d_in[2];   // [2,256]
  const float* b1  = (const float*)d_in[3];   // [256]
  const float* W2  = (const float*)d_in[4];   // [256,2304]
  const float* b2  = (const float*)d_in[5];   // [2304]
  float* out = (float*)d_out;
  short* W2p = (short*)d_ws;                  // 256*2560 bf16 = 1.31 MB

  prep_w2p<<<256, 256, 0, stream>>>(W2, W2p);
  ngconv_sweep<<<512, 256, 0, stream>>>(in, foa, W1, b1, W2p, b2, out);
}